// Round 1
// 611.619 us; speedup vs baseline: 1.0642x; 1.0642x over previous
//
#include <hip/hip_runtime.h>
#include <math.h>

#define ND 128
#define ED 64
#define LN_EPS 1e-5f
#define TE 64        // edges per block (edge kernel)
#define SXH 328      // edge LDS row stride (halves): 656B/row; as float stride = 164 dw
#define GSH 136      // gru f16 LDS row stride (halves)
#define GSF 132      // gru fp32 LDS row stride (floats)

typedef _Float16 f16;
typedef __attribute__((ext_vector_type(8))) _Float16 f16x8;
typedef __attribute__((ext_vector_type(4))) _Float16 f16x4;
typedef __attribute__((ext_vector_type(4))) float f32x4;

__device__ __forceinline__ float sigmoidf_(float x) { return 1.f / (1.f + expf(-x)); }

// ---- weight conversion: fp32 -> f16 (+transpose for W1,W2) ----
// W1f[n*320+k] = W1[k*128+n]; W2f[n*128+k] = W2[k*128+n]; Wih/Whh straight.
__global__ void convert_kernel(const float* __restrict__ W1, const float* __restrict__ W2,
                               const float* __restrict__ Wih, const float* __restrict__ Whh,
                               f16* __restrict__ W1f, f16* __restrict__ W2f,
                               f16* __restrict__ Wihf, f16* __restrict__ Whhf)
{
    int idx = blockIdx.x * 256 + threadIdx.x;
    if (idx < 40960) {
        int n = idx / 320, k = idx - n * 320;
        W1f[idx] = (f16)W1[k * 128 + n];
    } else if (idx < 57344) {
        int i2 = idx - 40960; int n = i2 >> 7, k = i2 & 127;
        W2f[i2] = (f16)W2[k * 128 + n];
    } else if (idx < 106496) {
        int i3 = idx - 57344;  Wihf[i3] = (f16)Wih[i3];
    } else if (idx < 155648) {
        int i4 = idx - 106496; Whhf[i4] = (f16)Whh[i4];
    }
}

// ---- node features fp32 -> f16 (one pass; edge kernel re-reads each row ~32x) ----
__global__ void nf16_kernel(const float* __restrict__ nf, f16* __restrict__ nf16, int n8) {
    int i = blockIdx.x * 256 + threadIdx.x;    // one thread per 8 floats
    if (i < n8) {
        float4 a = ((const float4*)nf)[2 * i];
        float4 b = ((const float4*)nf)[2 * i + 1];
        f16x8 h;
        h[0] = (f16)a.x; h[1] = (f16)a.y; h[2] = (f16)a.z; h[3] = (f16)a.w;
        h[4] = (f16)b.x; h[5] = (f16)b.y; h[6] = (f16)b.z; h[7] = (f16)b.w;
        ((f16x8*)nf16)[i] = h;
    }
}

// ---- CSR-style dst-sort: histogram -> scan -> scatter-rank ----
__global__ void hist_kernel(const int* __restrict__ eidx, int* __restrict__ cnt, int E) {
    int i = blockIdx.x * 256 + threadIdx.x;
    if (i < E) atomicAdd(&cnt[eidx[E + i]], 1);
}

__global__ __launch_bounds__(1024)
void scan_kernel(const int* __restrict__ cnt, int* __restrict__ woff, int N) {
    __shared__ int part[1024];
    const int t = threadIdx.x;
    const int CH = 40;
    int base = t * CH;
    int s = 0;
    for (int i = 0; i < CH; ++i) { int idx = base + i; if (idx < N) s += cnt[idx]; }
    part[t] = s;
    __syncthreads();
    for (int d = 1; d < 1024; d <<= 1) {
        int v = (t >= d) ? part[t - d] : 0;
        __syncthreads();
        part[t] += v;
        __syncthreads();
    }
    int run = (t == 0) ? 0 : part[t - 1];
    for (int i = 0; i < CH; ++i) {
        int idx = base + i;
        if (idx < N) { woff[idx] = run; run += cnt[idx]; }
    }
}

__global__ void scatter_kernel(const int* __restrict__ eidx, int* __restrict__ woff,
                               int* __restrict__ perm, int E) {
    int i = blockIdx.x * 256 + threadIdx.x;
    if (i < E) {
        int p = atomicAdd(&woff[eidx[E + i]], 1);
        perm[p] = i;
    }
}

// ---------------- edge message kernel (f16 MFMA, N-partitioned waves) ----------------
// 256 thr = 4 waves; 64 dst-sorted edges/block. Wave w owns cols [32w,32w+32) (2 N-tiles)
// over ALL 64 edges (4 M-tiles) -> each B-fragment load feeds 4 MFMAs.
__global__ __launch_bounds__(256, 3)
void edge_kernel(const f16* __restrict__ nf16, const int* __restrict__ eidx,
                 const float* __restrict__ ef, const int* __restrict__ perm,
                 const f16* __restrict__ W1f, const float* __restrict__ b1,
                 const float* __restrict__ ln_g, const float* __restrict__ ln_b,
                 const f16* __restrict__ W2f, const float* __restrict__ b2,
                 const float* __restrict__ gate_w, const float* __restrict__ gate_b,
                 float* __restrict__ agg, int E)
{
    __shared__ f16   sxh[TE * SXH];       // 41 KB: x tile f16; cols[0,128) reused for h', then fp32 messages
    __shared__ float sred[TE * 8];        // LN partials [row][w*2 + {p1,p2}]
    __shared__ float spart[TE][4];        // gate partials
    __shared__ float sg[TE];              // per-edge gate
    __shared__ int   se_s[TE], ssrc_s[TE], sdst_s[TE];

    const int tid  = threadIdx.x;
    const int lane = tid & 63;
    const int w    = __builtin_amdgcn_readfirstlane(tid >> 6);
    const int cb   = 32 * w;              // column base for this wave
    const int c    = lane & 15;
    const int quad = lane >> 4;
    const int e0   = blockIdx.x * TE;

    if (tid < TE) {
        int e = perm[e0 + tid];
        se_s[tid]   = e;
        ssrc_s[tid] = eidx[e];
        sdst_s[tid] = eidx[E + e];
    }
    __syncthreads();   // B0

    // ---- stage 64 rows x 320: [nf16[src] | nf16[dst] | ef], gate partials folded in ----
    {
        const int r = tid >> 2, q = tid & 3;     // 4 threads per row
        const f16*   srow = nf16 + (size_t)ssrc_s[r] * ND;
        const f16*   drow = nf16 + (size_t)sdst_s[r] * ND;
        const float* erow = ef + (size_t)se_s[r] * ED;
        f16* dp = sxh + r * SXH;
        #pragma unroll
        for (int i = 0; i < 4; ++i) {            // src cols [0,128), dst cols [128,256): f16 copy
            int ch = (q + 4 * i) * 8;
            *(f16x8*)(dp + ch)       = *(const f16x8*)(srow + ch);
            *(f16x8*)(dp + 128 + ch) = *(const f16x8*)(drow + ch);
        }
        float gp = 0.f;
        #pragma unroll
        for (int i = 0; i < 4; ++i) {            // ef cols [256,320): cvt + gate partial (fp32)
            int ec = (q + 4 * i) * 4;
            float4 v = *(const float4*)(erow + ec);
            f16x4 h4; h4[0] = (f16)v.x; h4[1] = (f16)v.y; h4[2] = (f16)v.z; h4[3] = (f16)v.w;
            *(f16x4*)(dp + 256 + ec) = h4;
            const float* gw = gate_w + ec;
            gp = fmaf(v.x, gw[0], gp); gp = fmaf(v.y, gw[1], gp);
            gp = fmaf(v.z, gw[2], gp); gp = fmaf(v.w, gw[3], gp);
        }
        spart[r][q] = gp;
    }
    __syncthreads();   // B1

    if (tid < TE)      // sg consumed after B5; B3/B4/B5 guarantee visibility
        sg[tid] = sigmoidf_(spart[tid][0] + spart[tid][1] + spart[tid][2] + spart[tid][3] + gate_b[0]);

    // ---- GEMM1: [64x320] @ [320x(32 cols/wave)] ----
    f32x4 acc[4][2];
    #pragma unroll
    for (int mt = 0; mt < 4; ++mt)
        #pragma unroll
        for (int nt = 0; nt < 2; ++nt) acc[mt][nt] = (f32x4){0.f, 0.f, 0.f, 0.f};

    #pragma unroll
    for (int ks = 0; ks < 10; ++ks) {
        f16x8 b0 = *(const f16x8*)(W1f + (cb + c) * 320 + ks * 32 + quad * 8);
        f16x8 b1v = *(const f16x8*)(W1f + (cb + 16 + c) * 320 + ks * 32 + quad * 8);
        #pragma unroll
        for (int mt = 0; mt < 4; ++mt) {
            f16x8 a = *(const f16x8*)(sxh + (16 * mt + c) * SXH + ks * 32 + quad * 8);
            acc[mt][0] = __builtin_amdgcn_mfma_f32_16x16x32_f16(a, b0,  acc[mt][0], 0, 0, 0);
            acc[mt][1] = __builtin_amdgcn_mfma_f32_16x16x32_f16(a, b1v, acc[mt][1], 0, 0, 0);
        }
    }

    // ---- bias + LN partials over this wave's 32 cols ----
    float b1c[2], gvc[2], bvc[2], b2c[2];
    #pragma unroll
    for (int nt = 0; nt < 2; ++nt) {
        int col = cb + nt * 16 + c;
        b1c[nt] = b1[col]; gvc[nt] = ln_g[col]; bvc[nt] = ln_b[col]; b2c[nt] = b2[col];
    }
    #pragma unroll
    for (int mt = 0; mt < 4; ++mt) {
        float p1[4] = {0, 0, 0, 0}, p2[4] = {0, 0, 0, 0};
        #pragma unroll
        for (int nt = 0; nt < 2; ++nt)
            #pragma unroll
            for (int r = 0; r < 4; ++r) {
                float vv = acc[mt][nt][r] + b1c[nt];
                acc[mt][nt][r] = vv;
                p1[r] += vv; p2[r] += vv * vv;
            }
        #pragma unroll
        for (int m = 1; m < 16; m <<= 1)
            #pragma unroll
            for (int r = 0; r < 4; ++r) {
                p1[r] += __shfl_xor(p1[r], m);
                p2[r] += __shfl_xor(p2[r], m);
            }
        if (c == 0) {
            #pragma unroll
            for (int r = 0; r < 4; ++r) {
                int row = 16 * mt + 4 * quad + r;
                sred[row * 8 + 2 * w + 0] = p1[r];
                sred[row * 8 + 2 * w + 1] = p2[r];
            }
        }
    }
    __syncthreads();   // B3

    // ---- LN finalize + ReLU; h' (f16) into cols [0,128) ----
    #pragma unroll
    for (int mt = 0; mt < 4; ++mt)
        #pragma unroll
        for (int r = 0; r < 4; ++r) {
            int row = 16 * mt + 4 * quad + r;
            f32x4 lo = *(const f32x4*)(sred + row * 8);
            f32x4 hi = *(const f32x4*)(sred + row * 8 + 4);
            float t1 = lo[0] + lo[2] + hi[0] + hi[2];
            float t2 = lo[1] + lo[3] + hi[1] + hi[3];
            float mu = t1 * (1.f / 128.f);
            float var = t2 * (1.f / 128.f) - mu * mu;
            float rs = rsqrtf(var + LN_EPS);
            #pragma unroll
            for (int nt = 0; nt < 2; ++nt) {
                float vv = (acc[mt][nt][r] - mu) * rs * gvc[nt] + bvc[nt];
                vv = vv > 0.f ? vv : 0.f;
                sxh[row * SXH + cb + nt * 16 + c] = (f16)vv;
            }
        }
    __syncthreads();   // B4

    // ---- GEMM2: [64x128] @ [128x(32 cols/wave)] ----
    f32x4 acc2[4][2];
    #pragma unroll
    for (int mt = 0; mt < 4; ++mt)
        #pragma unroll
        for (int nt = 0; nt < 2; ++nt) acc2[mt][nt] = (f32x4){0.f, 0.f, 0.f, 0.f};
    #pragma unroll
    for (int ks = 0; ks < 4; ++ks) {
        f16x8 b0 = *(const f16x8*)(W2f + (cb + c) * 128 + ks * 32 + quad * 8);
        f16x8 b1v = *(const f16x8*)(W2f + (cb + 16 + c) * 128 + ks * 32 + quad * 8);
        #pragma unroll
        for (int mt = 0; mt < 4; ++mt) {
            f16x8 a = *(const f16x8*)(sxh + (16 * mt + c) * SXH + ks * 32 + quad * 8);
            acc2[mt][0] = __builtin_amdgcn_mfma_f32_16x16x32_f16(a, b0,  acc2[mt][0], 0, 0, 0);
            acc2[mt][1] = __builtin_amdgcn_mfma_f32_16x16x32_f16(a, b1v, acc2[mt][1], 0, 0, 0);
        }
    }
    __syncthreads();   // B5: all h' reads done -> safe to overwrite tile with fp32 messages

    // ---- gated messages (fp32) into LDS ----
    float* smsg = (float*)sxh;   // stride 164 dw per row
    #pragma unroll
    for (int mt = 0; mt < 4; ++mt)
        #pragma unroll
        for (int r = 0; r < 4; ++r) {
            int row = 16 * mt + 4 * quad + r;
            float gr = sg[row];
            #pragma unroll
            for (int nt = 0; nt < 2; ++nt)
                smsg[row * 164 + cb + nt * 16 + c] = (acc2[mt][nt][r] + b2c[nt]) * gr;
        }
    __syncthreads();   // B6

    // ---- segment reduction over sorted dst: all 4 waves, 16 rows each, 2 cols/lane ----
    {
        const int rbase = 16 * w;
        const float* sm = smsg + rbase * 164;
        float run0 = sm[lane];
        float run1 = sm[64 + lane];
        int prev = __builtin_amdgcn_readfirstlane(sdst_s[rbase]);
        #pragma unroll
        for (int r = 1; r < 16; ++r) {
            int d = __builtin_amdgcn_readfirstlane(sdst_s[rbase + r]);
            float v0 = sm[r * 164 + lane];
            float v1 = sm[r * 164 + 64 + lane];
            if (d == prev) { run0 += v0; run1 += v1; }
            else {
                atomicAdd(agg + (size_t)prev * ND + lane,      run0);
                atomicAdd(agg + (size_t)prev * ND + 64 + lane, run1);
                run0 = v0; run1 = v1; prev = d;
            }
        }
        atomicAdd(agg + (size_t)prev * ND + lane,      run0);
        atomicAdd(agg + (size_t)prev * ND + 64 + lane, run1);
    }
}

// ---------------- GRU kernel (f16 MFMA) ----------------
// 256 thr = 4 waves; 32 nodes/block. Wave w owns gate-cols [32w,32w+32).
__global__ __launch_bounds__(256, 2)
void gru_kernel(const float* __restrict__ agg, const float* __restrict__ nf,
                const f16* __restrict__ Wihf, const float* __restrict__ b_ih,
                const f16* __restrict__ Whhf, const float* __restrict__ b_hh,
                float* __restrict__ out)
{
    __shared__ f16   sa[32 * GSH];
    __shared__ f16   sh[32 * GSH];
    __shared__ float shf[32 * GSF];   // fp32 h_prev for the z*h term

    const int tid  = threadIdx.x;
    const int lane = tid & 63;
    const int w    = __builtin_amdgcn_readfirstlane(tid >> 6);
    const int c    = lane & 15;
    const int quad = lane >> 4;
    const int n0   = blockIdx.x * 32;

    {
        const int r = tid >> 3, q = tid & 7;
        const float* arow = agg + (size_t)(n0 + r) * ND;
        const float* hrow = nf  + (size_t)(n0 + r) * ND;
        #pragma unroll
        for (int i = 0; i < 4; ++i) {
            int ec = (q + 8 * i) * 4;
            float4 va = *(const float4*)(arow + ec);
            f16x4 ha; ha[0] = (f16)va.x; ha[1] = (f16)va.y; ha[2] = (f16)va.z; ha[3] = (f16)va.w;
            *(f16x4*)(sa + r * GSH + ec) = ha;
            float4 vh = *(const float4*)(hrow + ec);
            f16x4 hh; hh[0] = (f16)vh.x; hh[1] = (f16)vh.y; hh[2] = (f16)vh.z; hh[3] = (f16)vh.w;
            *(f16x4*)(sh + r * GSH + ec) = hh;
            *(float4*)(shf + r * GSF + ec) = vh;
        }
    }
    __syncthreads();

    f32x4 aI[2][6], aH[2][6];   // [mt][gg*2+nt]
    #pragma unroll
    for (int mt = 0; mt < 2; ++mt)
        #pragma unroll
        for (int j = 0; j < 6; ++j) {
            aI[mt][j] = (f32x4){0.f, 0.f, 0.f, 0.f};
            aH[mt][j] = (f32x4){0.f, 0.f, 0.f, 0.f};
        }

    #pragma unroll
    for (int ks = 0; ks < 4; ++ks) {
        f16x8 fa[2], fh[2];
        #pragma unroll
        for (int mt = 0; mt < 2; ++mt) {
            fa[mt] = *(const f16x8*)(sa + (16 * mt + c) * GSH + ks * 32 + quad * 8);
            fh[mt] = *(const f16x8*)(sh + (16 * mt + c) * GSH + ks * 32 + quad * 8);
        }
        #pragma unroll
        for (int gg = 0; gg < 3; ++gg)
            #pragma unroll
            for (int nt = 0; nt < 2; ++nt) {
                int coln = gg * 128 + 32 * w + nt * 16 + c;
                f16x8 bI = *(const f16x8*)(Wihf + coln * 128 + ks * 32 + quad * 8);
                f16x8 bH = *(const f16x8*)(Whhf + coln * 128 + ks * 32 + quad * 8);
                #pragma unroll
                for (int mt = 0; mt < 2; ++mt) {
                    int j = gg * 2 + nt;
                    aI[mt][j] = __builtin_amdgcn_mfma_f32_16x16x32_f16(fa[mt], bI, aI[mt][j], 0, 0, 0);
                    aH[mt][j] = __builtin_amdgcn_mfma_f32_16x16x32_f16(fh[mt], bH, aH[mt][j], 0, 0, 0);
                }
            }
    }

    #pragma unroll
    for (int nt = 0; nt < 2; ++nt) {
        int col = 32 * w + nt * 16 + c;
        float bir = b_ih[col], biz = b_ih[128 + col], bin = b_ih[256 + col];
        float bhr = b_hh[col], bhz = b_hh[128 + col], bhn = b_hh[256 + col];
        #pragma unroll
        for (int mt = 0; mt < 2; ++mt)
            #pragma unroll
            for (int r = 0; r < 4; ++r) {
                int row = 16 * mt + 4 * quad + r;
                float rr = sigmoidf_(aI[mt][0 + nt][r] + bir + aH[mt][0 + nt][r] + bhr);
                float zz = sigmoidf_(aI[mt][2 + nt][r] + biz + aH[mt][2 + nt][r] + bhz);
                float nn = tanhf(aI[mt][4 + nt][r] + bin + rr * (aH[mt][4 + nt][r] + bhn));
                float hp = shf[row * GSF + col];
                out[(size_t)(n0 + row) * ND + col] = (1.f - zz) * nn + zz * hp;
            }
    }
}

extern "C" void kernel_launch(void* const* d_in, const int* in_sizes, int n_in,
                              void* d_out, int out_size, void* d_ws, size_t ws_size,
                              hipStream_t stream) {
    const float* nf     = (const float*)d_in[0];
    const int*   eidx   = (const int*)  d_in[1];
    const float* ef     = (const float*)d_in[2];
    const float* W1     = (const float*)d_in[3];
    const float* b1     = (const float*)d_in[4];
    const float* ln_g   = (const float*)d_in[5];
    const float* ln_b   = (const float*)d_in[6];
    const float* W2     = (const float*)d_in[7];
    const float* b2     = (const float*)d_in[8];
    const float* gate_w = (const float*)d_in[9];
    const float* gate_b = (const float*)d_in[10];
    const float* W_ih   = (const float*)d_in[11];
    const float* b_ih   = (const float*)d_in[12];
    const float* W_hh   = (const float*)d_in[13];
    const float* b_hh   = (const float*)d_in[14];
    float* out = (float*)d_out;

    const int N = in_sizes[0] / ND;   // 40000
    const int E = in_sizes[1] / 2;    // 640000

    char* ws = (char*)d_ws;
    float* agg = (float*)ws;          ws += (size_t)N * ND * 4;   // 20.48 MB
    f16* nf16 = (f16*)ws;             ws += (size_t)N * ND * 2;   // 10.24 MB
    f16* W1f  = (f16*)ws;             ws += 40960 * 2;
    f16* W2f  = (f16*)ws;             ws += 16384 * 2;
    f16* Wihf = (f16*)ws;             ws += 49152 * 2;
    f16* Whhf = (f16*)ws;             ws += 49152 * 2;
    int* cnt  = (int*)ws;             ws += 40960 * 4;
    int* woff = (int*)ws;             ws += 40960 * 4;
    int* perm = (int*)ws;             ws += (size_t)E * 4;        // 2.56 MB

    hipMemsetAsync(agg, 0, (size_t)N * ND * 4, stream);
    hipMemsetAsync(cnt, 0, (size_t)N * 4, stream);
    convert_kernel<<<608, 256, 0, stream>>>(W1, W2, W_ih, W_hh, W1f, W2f, Wihf, Whhf);
    const int n8 = N * ND / 8;
    nf16_kernel<<<(n8 + 255) / 256, 256, 0, stream>>>(nf, nf16, n8);
    hist_kernel<<<(E + 255) / 256, 256, 0, stream>>>(eidx, cnt, E);
    scan_kernel<<<1, 1024, 0, stream>>>(cnt, woff, N);
    scatter_kernel<<<(E + 255) / 256, 256, 0, stream>>>(eidx, woff, perm, E);
    edge_kernel<<<E / TE, 256, 0, stream>>>(nf16, eidx, ef, perm, W1f, b1, ln_g, ln_b,
                                            W2f, b2, gate_w, gate_b, agg, E);
    gru_kernel<<<N / 32, 256, 0, stream>>>(agg, nf, Wihf, b_ih, Whhf, b_hh, out);
}